// Round 3
// baseline (1628.143 us; speedup 1.0000x reference)
//
#include <hip/hip_runtime.h>
#include <hip/hip_fp16.h>

// GAT conv: N=100000, E=1.6M, IN_C=128, OUT_C=32, HEADS=4 (OC=128)
// Round 3: drop exact CSR (hist+scan+fill wrote 106MB HBM for 6.4MB payload).
// Coarse 64-row buckets with fixed-capacity slabs (no scan needed), then one
// block per bucket accumulates into a 64x128 fp32 LDS tile via ds_add_f32.
// x_proj stored fp16 to halve the edge-gather stream (819MB -> 410MB).

constexpr float NEG_SLOPE = 0.2f;
constexpr int TILE_ROWS = 64;       // rows per bucket (row>>6)
constexpr int SLAB = 1536;          // slab capacity per bucket (avg fill 1024)

__global__ __launch_bounds__(256) void k_transpose_w(const float* __restrict__ W,
                                                     float* __restrict__ Wt) {
    int i = blockIdx.x * 256 + threadIdx.x;
    if (i < 128 * 128) {
        int o = i >> 7, k = i & 127;
        Wt[k * 128 + o] = W[i];
    }
}

__global__ __launch_bounds__(256) void k_init_cur(int* __restrict__ cur, int nb) {
    int b = blockIdx.x * 256 + threadIdx.x;
    if (b < nb) cur[b] = b * SLAB;
}

// 64 nodes per block, 256 threads; thread (tx,ty) computes 8 nodes x 4 chans.
// Output written as fp16.
__global__ __launch_bounds__(256) void k_gemm(const float* __restrict__ x,
                                              const float* __restrict__ Wt,
                                              __half* __restrict__ xph, int N) {
    __shared__ float xs[64 * 128];
    int t = threadIdx.x;
    int nb = blockIdx.x * 64;
    const float4* x4 = (const float4*)x;
    float4* xs4 = (float4*)xs;
#pragma unroll
    for (int m = 0; m < 8; ++m) {
        int idx = t + 256 * m;
        int nl = idx >> 5, kk = idx & 31;
        int n = nb + nl;
        float4 v = make_float4(0.f, 0.f, 0.f, 0.f);
        if (n < N) v = x4[(size_t)n * 32 + kk];
        xs4[idx] = v;
    }
    __syncthreads();
    int tx = t & 31, ty = t >> 5;
    float acc[8][4];
#pragma unroll
    for (int i = 0; i < 8; ++i)
#pragma unroll
        for (int j = 0; j < 4; ++j) acc[i][j] = 0.f;
#pragma unroll 4
    for (int k = 0; k < 128; ++k) {
        float w0 = Wt[k * 128 + tx];
        float w1 = Wt[k * 128 + tx + 32];
        float w2 = Wt[k * 128 + tx + 64];
        float w3 = Wt[k * 128 + tx + 96];
#pragma unroll
        for (int i = 0; i < 8; ++i) {
            float xk = xs[(ty * 8 + i) * 128 + k];
            acc[i][0] += xk * w0;
            acc[i][1] += xk * w1;
            acc[i][2] += xk * w2;
            acc[i][3] += xk * w3;
        }
    }
#pragma unroll
    for (int i = 0; i < 8; ++i) {
        int n = nb + ty * 8 + i;
        if (n < N) {
#pragma unroll
            for (int j = 0; j < 4; ++j)
                xph[(size_t)n * 128 + tx + 32 * j] = __float2half(acc[i][j]);
        }
    }
}

// One thread per (n,h): l = <xp[n,h,:], att_l[h,:]>, r likewise. xp is fp16.
__global__ __launch_bounds__(256) void k_lr(const __half* __restrict__ xph,
                                            const float* __restrict__ attl,
                                            const float* __restrict__ attr,
                                            float* __restrict__ l, float* __restrict__ r,
                                            int N) {
    int gid = blockIdx.x * 256 + threadIdx.x;
    if (gid >= N * 4) return;
    int h = gid & 3;
    const __half2* rowp = (const __half2*)xph + (size_t)(gid >> 2) * 64 + h * 16;
    const float2* al = (const float2*)attl + h * 16;
    const float2* ar = (const float2*)attr + h * 16;
    float dl = 0.f, dr = 0.f;
#pragma unroll
    for (int q = 0; q < 16; ++q) {
        float2 v = __half22float2(rowp[q]);
        float2 a = al[q];
        float2 b = ar[q];
        dl += v.x * a.x + v.y * a.y;
        dr += v.x * b.x + v.y * b.y;
    }
    l[gid] = dl;
    r[gid] = dr;
}

// Bucket edges into 64-row slabs: packed = (col<<6) | (row&63).
__global__ __launch_bounds__(256) void k_fill(const int* __restrict__ ei,
                                              int* __restrict__ cur,
                                              unsigned int* __restrict__ slab, int E) {
    int e = blockIdx.x * 256 + threadIdx.x;
    if (e >= E) return;
    int row = ei[e], col = ei[E + e];
    int b = row >> 6;
    int pos = atomicAdd(&cur[b], 1);
    slab[pos] = ((unsigned int)col << 6) | (unsigned int)(row & 63);
}

// One block per bucket. 512 threads = 8 waves; one wave per edge.
// Lane li covers channels li and li+64 (2-way LDS bank aliasing = free).
__global__ __launch_bounds__(512) void k_tile(const int* __restrict__ cur,
                                              const unsigned int* __restrict__ slab,
                                              const float* __restrict__ l,
                                              const float* __restrict__ r,
                                              const __half* __restrict__ xph,
                                              const float* __restrict__ bias,
                                              float* __restrict__ out, int N) {
    __shared__ float acc[TILE_ROWS * 128];
    __shared__ float den[TILE_ROWS * 4];
    __shared__ float l_s[TILE_ROWS * 4];
    __shared__ float bias_s[128];

    int b = blockIdx.x;
    int base = b * TILE_ROWS;
    int rows = min(TILE_ROWS, N - base);
    int t = threadIdx.x;

    // init
    for (int i = t; i < TILE_ROWS * 128; i += 512) acc[i] = 0.f;
    for (int i = t; i < TILE_ROWS * 4; i += 512) den[i] = 0.f;
    for (int i = t; i < rows * 4; i += 512) l_s[i] = l[base * 4 + i];
    if (t < 128) bias_s[t] = bias[t];
    __syncthreads();

    int start = b * SLAB;
    int end = cur[b];
    int wave = t >> 6;
    int li = t & 63;
    int h0 = li >> 5;          // head of channel li (0 or 1)

    for (int i = start + wave; i < end; i += 8) {
        unsigned int p = slab[i];
        int rl = p & 63;
        int col = (int)(p >> 6);
        float a0 = l_s[rl * 4 + h0]     + r[col * 4 + h0];
        float a1 = l_s[rl * 4 + h0 + 2] + r[col * 4 + h0 + 2];
        a0 = a0 >= 0.f ? a0 : NEG_SLOPE * a0;
        a1 = a1 >= 0.f ? a1 : NEG_SLOPE * a1;
        float w0 = __expf(a0);
        float w1 = __expf(a1);
        float x0 = __half2float(xph[(size_t)col * 128 + li]);
        float x1 = __half2float(xph[(size_t)col * 128 + li + 64]);
        atomicAdd(&acc[rl * 128 + li], w0 * x0);
        atomicAdd(&acc[rl * 128 + li + 64], w1 * x1);
        if (li == 0 || li == 32) {
            atomicAdd(&den[rl * 4 + h0], w0);
            atomicAdd(&den[rl * 4 + h0 + 2], w1);
        }
    }
    __syncthreads();

    for (int i = t; i < rows * 128; i += 512) {
        int rl = i >> 7, ch = i & 127;
        int h = ch >> 5;
        out[(size_t)(base + rl) * 128 + ch] =
            acc[i] / (den[rl * 4 + h] + 1e-16f) + bias_s[ch];
    }
}

extern "C" void kernel_launch(void* const* d_in, const int* in_sizes, int n_in,
                              void* d_out, int out_size, void* d_ws, size_t ws_size,
                              hipStream_t stream) {
    const float* x    = (const float*)d_in[0];
    const int*   ei   = (const int*)d_in[1];
    const float* W    = (const float*)d_in[2];
    const float* attl = (const float*)d_in[3];
    const float* attr = (const float*)d_in[4];
    const float* bias = (const float*)d_in[5];
    int N = in_sizes[0] / 128;
    int E = in_sizes[1] / 2;
    int nbuckets = (N + TILE_ROWS - 1) / TILE_ROWS;

    char* ws = (char*)d_ws;
    __half* xph = (__half*)ws;         ws += (size_t)N * 128 * 2;        // 25.6 MB
    float* l    = (float*)ws;          ws += (size_t)N * 4 * 4;
    float* r    = (float*)ws;          ws += (size_t)N * 4 * 4;
    float* Wt   = (float*)ws;          ws += 128 * 128 * 4;
    int* cur    = (int*)ws;            ws += (size_t)nbuckets * 4;
    unsigned int* slab = (unsigned int*)ws; ws += (size_t)nbuckets * SLAB * 4; // 9.6 MB

    float* out = (float*)d_out;

    k_init_cur<<<(nbuckets + 255) / 256, 256, 0, stream>>>(cur, nbuckets);
    k_transpose_w<<<64, 256, 0, stream>>>(W, Wt);
    k_gemm<<<(N + 63) / 64, 256, 0, stream>>>(x, Wt, xph, N);
    k_lr<<<(N * 4 + 255) / 256, 256, 0, stream>>>(xph, attl, attr, l, r, N);
    k_fill<<<(E + 255) / 256, 256, 0, stream>>>(ei, cur, slab, E);
    k_tile<<<nbuckets, 512, 0, stream>>>(cur, slab, l, r, xph, bias, out, N);
}

// Round 4
// 519.085 us; speedup vs baseline: 3.1366x; 3.1366x over previous
//
#include <hip/hip_runtime.h>
#include <hip/hip_fp16.h>

// GAT conv: N=100000, E=1.6M, IN_C=128, OUT_C=32, HEADS=4 (OC=128)
// Round 4: Round-3 coarse bucket fill (64-row slabs, packed (col<<6)|rowlocal)
// + per-block LDS counting sort + Round-2-style one-wave-per-row REGISTER
// accumulation (Round 3's 204.8M ds_add_f32 were LDS-atomic-pipe serialized:
// 1254us at VALUBusy 7%). Denom + normalize + bias fused into the row pass.

constexpr float NEG_SLOPE = 0.2f;
constexpr int TILE_ROWS = 64;       // rows per bucket (row>>6)
constexpr int SLAB = 2048;          // slab capacity per bucket (avg fill 1024)

__global__ __launch_bounds__(256) void k_transpose_w(const float* __restrict__ W,
                                                     float* __restrict__ Wt) {
    int i = blockIdx.x * 256 + threadIdx.x;
    if (i < 128 * 128) {
        int o = i >> 7, k = i & 127;
        Wt[k * 128 + o] = W[i];
    }
}

__global__ __launch_bounds__(256) void k_init_cur(int* __restrict__ cur, int nb) {
    int b = blockIdx.x * 256 + threadIdx.x;
    if (b < nb) cur[b] = b * SLAB;
}

// 64 nodes per block, 256 threads; thread (tx,ty) computes 8 nodes x 4 chans.
__global__ __launch_bounds__(256) void k_gemm(const float* __restrict__ x,
                                              const float* __restrict__ Wt,
                                              __half* __restrict__ xph, int N) {
    __shared__ float xs[64 * 128];
    int t = threadIdx.x;
    int nb = blockIdx.x * 64;
    const float4* x4 = (const float4*)x;
    float4* xs4 = (float4*)xs;
#pragma unroll
    for (int m = 0; m < 8; ++m) {
        int idx = t + 256 * m;
        int nl = idx >> 5, kk = idx & 31;
        int n = nb + nl;
        float4 v = make_float4(0.f, 0.f, 0.f, 0.f);
        if (n < N) v = x4[(size_t)n * 32 + kk];
        xs4[idx] = v;
    }
    __syncthreads();
    int tx = t & 31, ty = t >> 5;
    float acc[8][4];
#pragma unroll
    for (int i = 0; i < 8; ++i)
#pragma unroll
        for (int j = 0; j < 4; ++j) acc[i][j] = 0.f;
#pragma unroll 4
    for (int k = 0; k < 128; ++k) {
        float w0 = Wt[k * 128 + tx];
        float w1 = Wt[k * 128 + tx + 32];
        float w2 = Wt[k * 128 + tx + 64];
        float w3 = Wt[k * 128 + tx + 96];
#pragma unroll
        for (int i = 0; i < 8; ++i) {
            float xk = xs[(ty * 8 + i) * 128 + k];
            acc[i][0] += xk * w0;
            acc[i][1] += xk * w1;
            acc[i][2] += xk * w2;
            acc[i][3] += xk * w3;
        }
    }
#pragma unroll
    for (int i = 0; i < 8; ++i) {
        int n = nb + ty * 8 + i;
        if (n < N) {
#pragma unroll
            for (int j = 0; j < 4; ++j)
                xph[(size_t)n * 128 + tx + 32 * j] = __float2half(acc[i][j]);
        }
    }
}

// One thread per (n,h): l = <xp[n,h,:], att_l[h,:]>, r likewise. xp is fp16.
__global__ __launch_bounds__(256) void k_lr(const __half* __restrict__ xph,
                                            const float* __restrict__ attl,
                                            const float* __restrict__ attr,
                                            float* __restrict__ l, float* __restrict__ r,
                                            int N) {
    int gid = blockIdx.x * 256 + threadIdx.x;
    if (gid >= N * 4) return;
    int h = gid & 3;
    const __half2* rowp = (const __half2*)xph + (size_t)(gid >> 2) * 64 + h * 16;
    const float2* al = (const float2*)attl + h * 16;
    const float2* ar = (const float2*)attr + h * 16;
    float dl = 0.f, dr = 0.f;
#pragma unroll
    for (int q = 0; q < 16; ++q) {
        float2 v = __half22float2(rowp[q]);
        float2 a = al[q];
        float2 b = ar[q];
        dl += v.x * a.x + v.y * a.y;
        dr += v.x * b.x + v.y * b.y;
    }
    l[gid] = dl;
    r[gid] = dr;
}

// Bucket edges into 64-row slabs: packed = (col<<6) | (row&63).
__global__ __launch_bounds__(256) void k_fill(const int* __restrict__ ei,
                                              int* __restrict__ cur,
                                              unsigned int* __restrict__ slab, int E) {
    int e = blockIdx.x * 256 + threadIdx.x;
    if (e >= E) return;
    int row = ei[e], col = ei[E + e];
    int b = row >> 6;
    int pos = atomicAdd(&cur[b], 1);
    if (pos < (b + 1) * SLAB)   // statistically never overflows (Poisson 1024)
        slab[pos] = ((unsigned int)col << 6) | (unsigned int)(row & 63);
}

// One block per bucket, 512 threads = 8 waves.
// Phase A: LDS counting sort of the bucket's edges by local row.
// Phase B: one wave per row, register float4 accumulation (2 edges in flight
// via wave halves), shfl_xor(32) combine, fused normalize + bias.
__global__ __launch_bounds__(512) void k_tile(const int* __restrict__ cur,
                                              const unsigned int* __restrict__ slab,
                                              const float* __restrict__ l,
                                              const float* __restrict__ r,
                                              const __half* __restrict__ xph,
                                              const float* __restrict__ bias,
                                              float* __restrict__ out, int N) {
    __shared__ unsigned int s_packed[SLAB];   // 8 KB
    __shared__ int s_col[SLAB];               // 8 KB (cols ordered by local row)
    __shared__ int s_start[TILE_ROWS + 1];
    __shared__ int s_cursor[TILE_ROWS];
    __shared__ int s_cnt[TILE_ROWS];

    int b = blockIdx.x;
    int base = b * TILE_ROWS;
    int t = threadIdx.x;
    int nedge = cur[b] - b * SLAB;
    if (nedge > SLAB) nedge = SLAB;

    if (t < TILE_ROWS) s_cnt[t] = 0;
    __syncthreads();
    for (int i = t; i < nedge; i += 512) {
        unsigned int p = slab[b * SLAB + i];
        s_packed[i] = p;
        atomicAdd(&s_cnt[p & 63], 1);
    }
    __syncthreads();
    if (t < 64) {
        int c = s_cnt[t];
        int v = c;
#pragma unroll
        for (int off = 1; off < 64; off <<= 1) {
            int u = __shfl_up(v, off);
            if (t >= off) v += u;
        }
        s_start[t + 1] = v;
        if (t == 0) s_start[0] = 0;
        s_cursor[t] = v - c;   // exclusive
    }
    __syncthreads();
    for (int i = t; i < nedge; i += 512) {
        unsigned int p = s_packed[i];
        int pos = atomicAdd(&s_cursor[p & 63], 1);
        s_col[pos] = (int)(p >> 6);
    }
    __syncthreads();

    int wave = t >> 6;
    int lane = t & 63;
    int half = lane >> 5;      // which half-wave: alternate edges
    int li = lane & 31;        // channel group: chans 4li..4li+3
    int h = li >> 3;           // head of this channel group
    int rows = min(TILE_ROWS, N - base);
    const float2* xp2 = (const float2*)xph;   // 8B = 4 halves per lane

    for (int rl = wave; rl < rows; rl += 8) {
        int s0 = s_start[rl], s1 = s_start[rl + 1];
        float4 lv = ((const float4*)l)[base + rl];     // broadcast
        float lh = h == 0 ? lv.x : h == 1 ? lv.y : h == 2 ? lv.z : lv.w;
        float4 acc = make_float4(0.f, 0.f, 0.f, 0.f);
        float dsum = 0.f;
#pragma unroll 2
        for (int i = s0 + half; i < s1; i += 2) {
            int col = s_col[i];                        // broadcast LDS read
            float4 rv = ((const float4*)r)[col];       // broadcast 16B load
            float rh = h == 0 ? rv.x : h == 1 ? rv.y : h == 2 ? rv.z : rv.w;
            float a = lh + rh;
            a = a >= 0.f ? a : NEG_SLOPE * a;
            float w = __expf(a);
            float2 raw = xp2[(size_t)col * 32 + li];   // coalesced 256B/edge
            __half2 p0 = *(__half2*)&raw.x;
            __half2 p1 = *(__half2*)&raw.y;
            float2 f0 = __half22float2(p0);
            float2 f1 = __half22float2(p1);
            acc.x += w * f0.x;
            acc.y += w * f0.y;
            acc.z += w * f1.x;
            acc.w += w * f1.y;
            dsum += w;
        }
        acc.x += __shfl_xor(acc.x, 32);
        acc.y += __shfl_xor(acc.y, 32);
        acc.z += __shfl_xor(acc.z, 32);
        acc.w += __shfl_xor(acc.w, 32);
        dsum += __shfl_xor(dsum, 32);
        if (half == 0) {
            float inv = 1.f / (dsum + 1e-16f);
            float4 bv = ((const float4*)bias)[li];
            float4 o;
            o.x = acc.x * inv + bv.x;
            o.y = acc.y * inv + bv.y;
            o.z = acc.z * inv + bv.z;
            o.w = acc.w * inv + bv.w;
            ((float4*)out)[(size_t)(base + rl) * 32 + li] = o;
        }
    }
}

extern "C" void kernel_launch(void* const* d_in, const int* in_sizes, int n_in,
                              void* d_out, int out_size, void* d_ws, size_t ws_size,
                              hipStream_t stream) {
    const float* x    = (const float*)d_in[0];
    const int*   ei   = (const int*)d_in[1];
    const float* W    = (const float*)d_in[2];
    const float* attl = (const float*)d_in[3];
    const float* attr = (const float*)d_in[4];
    const float* bias = (const float*)d_in[5];
    int N = in_sizes[0] / 128;
    int E = in_sizes[1] / 2;
    int nbuckets = (N + TILE_ROWS - 1) / TILE_ROWS;

    char* ws = (char*)d_ws;
    __half* xph = (__half*)ws;              ws += (size_t)N * 128 * 2;         // 25.6 MB
    float* l    = (float*)ws;               ws += (size_t)N * 4 * 4;
    float* r    = (float*)ws;               ws += (size_t)N * 4 * 4;
    float* Wt   = (float*)ws;               ws += 128 * 128 * 4;
    int* cur    = (int*)ws;                 ws += (size_t)nbuckets * 4;
    unsigned int* slab = (unsigned int*)ws; ws += (size_t)nbuckets * SLAB * 4; // 12.8 MB

    float* out = (float*)d_out;

    k_init_cur<<<(nbuckets + 255) / 256, 256, 0, stream>>>(cur, nbuckets);
    k_transpose_w<<<64, 256, 0, stream>>>(W, Wt);
    k_gemm<<<(N + 63) / 64, 256, 0, stream>>>(x, Wt, xph, N);
    k_lr<<<(N * 4 + 255) / 256, 256, 0, stream>>>(xph, attl, attr, l, r, N);
    k_fill<<<(E + 255) / 256, 256, 0, stream>>>(ei, cur, slab, E);
    k_tile<<<nbuckets, 512, 0, stream>>>(cur, slab, l, r, xph, bias, out, N);
}

// Round 5
// 367.124 us; speedup vs baseline: 4.4349x; 1.4139x over previous
//
#include <hip/hip_runtime.h>
#include <hip/hip_fp16.h>

// GAT conv: N=100000, E=1.6M, IN_C=128, OUT_C=32, HEADS=4 (OC=128)
// Round 5: k_fill was 240us at VALUBusy 0.3%, WRITE 75MB for 6.4MB payload —
// hot-cursor contention (1024 atomics/counter) + cross-XCD false sharing on
// slab lines. Fix: 8-way group-partitioned slabs (group = blockIdx&7 ~ XCD):
// private cursors (8x less contention) and single-XCD slab lines (write
// combining works). k_tile concatenates the 8 segments; its counting-sort +
// register row-accumulation (Round 4) is unchanged.

constexpr float NEG_SLOPE = 0.2f;
constexpr int TILE_ROWS = 64;       // rows per bucket (row>>6)
constexpr int NGROUP = 8;           // slab partitions (~XCDs)
constexpr int CAP = 256;            // per-(bucket,group) capacity; avg fill 128
constexpr int SLAB = 2048;          // max edges per bucket in LDS (8*CAP)

__global__ __launch_bounds__(256) void k_transpose_w(const float* __restrict__ W,
                                                     float* __restrict__ Wt) {
    int i = blockIdx.x * 256 + threadIdx.x;
    if (i < 128 * 128) {
        int o = i >> 7, k = i & 127;
        Wt[k * 128 + o] = W[i];
    }
}

// 64 nodes per block, 256 threads; thread (tx,ty) computes 8 nodes x 4 chans.
__global__ __launch_bounds__(256) void k_gemm(const float* __restrict__ x,
                                              const float* __restrict__ Wt,
                                              __half* __restrict__ xph, int N) {
    __shared__ float xs[64 * 128];
    int t = threadIdx.x;
    int nb = blockIdx.x * 64;
    const float4* x4 = (const float4*)x;
    float4* xs4 = (float4*)xs;
#pragma unroll
    for (int m = 0; m < 8; ++m) {
        int idx = t + 256 * m;
        int nl = idx >> 5, kk = idx & 31;
        int n = nb + nl;
        float4 v = make_float4(0.f, 0.f, 0.f, 0.f);
        if (n < N) v = x4[(size_t)n * 32 + kk];
        xs4[idx] = v;
    }
    __syncthreads();
    int tx = t & 31, ty = t >> 5;
    float acc[8][4];
#pragma unroll
    for (int i = 0; i < 8; ++i)
#pragma unroll
        for (int j = 0; j < 4; ++j) acc[i][j] = 0.f;
#pragma unroll 4
    for (int k = 0; k < 128; ++k) {
        float w0 = Wt[k * 128 + tx];
        float w1 = Wt[k * 128 + tx + 32];
        float w2 = Wt[k * 128 + tx + 64];
        float w3 = Wt[k * 128 + tx + 96];
#pragma unroll
        for (int i = 0; i < 8; ++i) {
            float xk = xs[(ty * 8 + i) * 128 + k];
            acc[i][0] += xk * w0;
            acc[i][1] += xk * w1;
            acc[i][2] += xk * w2;
            acc[i][3] += xk * w3;
        }
    }
#pragma unroll
    for (int i = 0; i < 8; ++i) {
        int n = nb + ty * 8 + i;
        if (n < N) {
#pragma unroll
            for (int j = 0; j < 4; ++j)
                xph[(size_t)n * 128 + tx + 32 * j] = __float2half(acc[i][j]);
        }
    }
}

// One thread per (n,h): l = <xp[n,h,:], att_l[h,:]>, r likewise. xp is fp16.
__global__ __launch_bounds__(256) void k_lr(const __half* __restrict__ xph,
                                            const float* __restrict__ attl,
                                            const float* __restrict__ attr,
                                            float* __restrict__ l, float* __restrict__ r,
                                            int N) {
    int gid = blockIdx.x * 256 + threadIdx.x;
    if (gid >= N * 4) return;
    int h = gid & 3;
    const __half2* rowp = (const __half2*)xph + (size_t)(gid >> 2) * 64 + h * 16;
    const float2* al = (const float2*)attl + h * 16;
    const float2* ar = (const float2*)attr + h * 16;
    float dl = 0.f, dr = 0.f;
#pragma unroll
    for (int q = 0; q < 16; ++q) {
        float2 v = __half22float2(rowp[q]);
        float2 a = al[q];
        float2 b = ar[q];
        dl += v.x * a.x + v.y * a.y;
        dr += v.x * b.x + v.y * b.y;
    }
    l[gid] = dl;
    r[gid] = dr;
}

// Bucket edges into group-partitioned 64-row slabs.
// packed = (col<<6) | (row&63); slot (bucket b, group g) at (b*8+g)*CAP.
__global__ __launch_bounds__(256) void k_fill(const int* __restrict__ ei,
                                              int* __restrict__ cur,
                                              unsigned int* __restrict__ slab, int E) {
    int tid = blockIdx.x * 256 + threadIdx.x;
    int g = blockIdx.x & (NGROUP - 1);
    int e0 = tid * 4;
    if (e0 + 3 >= E) {
        for (int e = e0; e < E; ++e) {
            int row = ei[e], col = ei[E + e];
            int b = row >> 6;
            int pos = atomicAdd(&cur[b * NGROUP + g], 1);
            if (pos < CAP)
                slab[(b * NGROUP + g) * CAP + pos] =
                    ((unsigned int)col << 6) | (unsigned int)(row & 63);
        }
        return;
    }
    int4 rows = ((const int4*)ei)[tid];
    int4 cols = ((const int4*)(ei + E))[tid];
    int rr[4] = {rows.x, rows.y, rows.z, rows.w};
    int cc[4] = {cols.x, cols.y, cols.z, cols.w};
#pragma unroll
    for (int j = 0; j < 4; ++j) {
        int b = rr[j] >> 6;
        int pos = atomicAdd(&cur[b * NGROUP + g], 1);
        if (pos < CAP)   // Poisson(128) vs 256: never in practice
            slab[(b * NGROUP + g) * CAP + pos] =
                ((unsigned int)cc[j] << 6) | (unsigned int)(rr[j] & 63);
    }
}

// One block per bucket, 512 threads = 8 waves.
// Phase A: concat 8 slab segments into LDS, counting-sort by local row.
// Phase B: one wave per row, register float4 accumulation (2 edges in flight
// via wave halves), shfl_xor(32) combine, fused normalize + bias.
__global__ __launch_bounds__(512) void k_tile(const int* __restrict__ cur,
                                              const unsigned int* __restrict__ slab,
                                              const float* __restrict__ l,
                                              const float* __restrict__ r,
                                              const __half* __restrict__ xph,
                                              const float* __restrict__ bias,
                                              float* __restrict__ out, int N) {
    __shared__ unsigned int s_packed[SLAB];   // 8 KB
    __shared__ int s_col[SLAB];               // 8 KB (cols ordered by local row)
    __shared__ int s_start[TILE_ROWS + 1];
    __shared__ int s_cursor[TILE_ROWS];
    __shared__ int s_cnt[TILE_ROWS];

    int b = blockIdx.x;
    int base = b * TILE_ROWS;
    int t = threadIdx.x;

    if (t < TILE_ROWS) s_cnt[t] = 0;
    __syncthreads();

    // concat the 8 group segments; histogram local rows on the way in
    int cnts[NGROUP], offs[NGROUP];
    int tot = 0;
#pragma unroll
    for (int g = 0; g < NGROUP; ++g) {
        int c = cur[b * NGROUP + g];
        if (c > CAP) c = CAP;
        cnts[g] = c;
        offs[g] = tot;
        tot += c;
    }
#pragma unroll
    for (int g = 0; g < NGROUP; ++g) {
        for (int i = t; i < cnts[g]; i += 512) {
            unsigned int p = slab[(b * NGROUP + g) * CAP + i];
            s_packed[offs[g] + i] = p;
            atomicAdd(&s_cnt[p & 63], 1);
        }
    }
    __syncthreads();
    if (t < 64) {
        int c = s_cnt[t];
        int v = c;
#pragma unroll
        for (int off = 1; off < 64; off <<= 1) {
            int u = __shfl_up(v, off);
            if (t >= off) v += u;
        }
        s_start[t + 1] = v;
        if (t == 0) s_start[0] = 0;
        s_cursor[t] = v - c;   // exclusive
    }
    __syncthreads();
    for (int i = t; i < tot; i += 512) {
        unsigned int p = s_packed[i];
        int pos = atomicAdd(&s_cursor[p & 63], 1);
        s_col[pos] = (int)(p >> 6);
    }
    __syncthreads();

    int wave = t >> 6;
    int lane = t & 63;
    int half = lane >> 5;      // which half-wave: alternate edges
    int li = lane & 31;        // channel group: chans 4li..4li+3
    int h = li >> 3;           // head of this channel group
    int rows = min(TILE_ROWS, N - base);
    const float2* xp2 = (const float2*)xph;   // 8B = 4 halves per lane

    for (int rl = wave; rl < rows; rl += 8) {
        int s0 = s_start[rl], s1 = s_start[rl + 1];
        float4 lv = ((const float4*)l)[base + rl];     // broadcast
        float lh = h == 0 ? lv.x : h == 1 ? lv.y : h == 2 ? lv.z : lv.w;
        float4 acc = make_float4(0.f, 0.f, 0.f, 0.f);
        float dsum = 0.f;
#pragma unroll 2
        for (int i = s0 + half; i < s1; i += 2) {
            int col = s_col[i];                        // broadcast LDS read
            float4 rv = ((const float4*)r)[col];       // broadcast 16B load
            float rh = h == 0 ? rv.x : h == 1 ? rv.y : h == 2 ? rv.z : rv.w;
            float a = lh + rh;
            a = a >= 0.f ? a : NEG_SLOPE * a;
            float w = __expf(a);
            float2 raw = xp2[(size_t)col * 32 + li];   // coalesced 256B/edge
            __half2 p0 = *(__half2*)&raw.x;
            __half2 p1 = *(__half2*)&raw.y;
            float2 f0 = __half22float2(p0);
            float2 f1 = __half22float2(p1);
            acc.x += w * f0.x;
            acc.y += w * f0.y;
            acc.z += w * f1.x;
            acc.w += w * f1.y;
            dsum += w;
        }
        acc.x += __shfl_xor(acc.x, 32);
        acc.y += __shfl_xor(acc.y, 32);
        acc.z += __shfl_xor(acc.z, 32);
        acc.w += __shfl_xor(acc.w, 32);
        dsum += __shfl_xor(dsum, 32);
        if (half == 0) {
            float inv = 1.f / (dsum + 1e-16f);
            float4 bv = ((const float4*)bias)[li];
            float4 o;
            o.x = acc.x * inv + bv.x;
            o.y = acc.y * inv + bv.y;
            o.z = acc.z * inv + bv.z;
            o.w = acc.w * inv + bv.w;
            ((float4*)out)[(size_t)(base + rl) * 32 + li] = o;
        }
    }
}

extern "C" void kernel_launch(void* const* d_in, const int* in_sizes, int n_in,
                              void* d_out, int out_size, void* d_ws, size_t ws_size,
                              hipStream_t stream) {
    const float* x    = (const float*)d_in[0];
    const int*   ei   = (const int*)d_in[1];
    const float* W    = (const float*)d_in[2];
    const float* attl = (const float*)d_in[3];
    const float* attr = (const float*)d_in[4];
    const float* bias = (const float*)d_in[5];
    int N = in_sizes[0] / 128;
    int E = in_sizes[1] / 2;
    int nbuckets = (N + TILE_ROWS - 1) / TILE_ROWS;

    char* ws = (char*)d_ws;
    __half* xph = (__half*)ws;              ws += (size_t)N * 128 * 2;         // 25.6 MB
    float* l    = (float*)ws;               ws += (size_t)N * 4 * 4;
    float* r    = (float*)ws;               ws += (size_t)N * 4 * 4;
    float* Wt   = (float*)ws;               ws += 128 * 128 * 4;
    int* cur    = (int*)ws;                 ws += (size_t)nbuckets * NGROUP * 4;
    unsigned int* slab = (unsigned int*)ws; ws += (size_t)nbuckets * NGROUP * CAP * 4; // 12.8 MB

    float* out = (float*)d_out;

    hipMemsetAsync(cur, 0, (size_t)nbuckets * NGROUP * sizeof(int), stream);
    k_transpose_w<<<64, 256, 0, stream>>>(W, Wt);
    k_gemm<<<(N + 63) / 64, 256, 0, stream>>>(x, Wt, xph, N);
    k_lr<<<(N * 4 + 255) / 256, 256, 0, stream>>>(xph, attl, attr, l, r, N);
    k_fill<<<(E / 4 + 255) / 256, 256, 0, stream>>>(ei, cur, slab, E);
    k_tile<<<nbuckets, 512, 0, stream>>>(cur, slab, l, r, xph, bias, out, N);
}

// Round 6
// 292.002 us; speedup vs baseline: 5.5758x; 1.2573x over previous
//
#include <hip/hip_runtime.h>
#include <hip/hip_fp16.h>

// GAT conv: N=100000, E=1.6M, IN_C=128, OUT_C=32, HEADS=4 (OC=128)
// Round 6:
//  - k_gemm: MFMA bf16 16x16x32 (4 waves x 16 nodes/block), W pre-cast to
//    bf16; l/r fused into the epilogue via shfl reductions (k_lr + transpose
//    kernels deleted).
//  - k_fill: NGROUP 8->32 (group = (blockIdx&7)*4 | waveid&3): same XCD
//    affinity per slab segment, 4x less cursor contention.
//  - k_tile: 4 edges in flight per wave (quarter-waves; lane reads float4 =
//    8 fp16 channels), shfl_xor(16,32) combine. Was latency-bound at
//    VALUBusy 32% with only 2 chains/wave.

constexpr float NEG_SLOPE = 0.2f;
constexpr int TILE_ROWS = 64;       // rows per bucket (row>>6)
constexpr int NGROUP = 32;          // slab partitions: 8 XCD classes x 4 waves
constexpr int CAP = 96;             // per-(bucket,group) capacity; mean 32
constexpr int SLAB = 2048;          // max edges per bucket staged in LDS

typedef __attribute__((ext_vector_type(8))) short short8;
typedef __attribute__((ext_vector_type(4))) float f32x4;

__device__ inline short f2bf(float f) {
    unsigned u = __float_as_uint(f);
    return (short)((u + 0x7fffu + ((u >> 16) & 1u)) >> 16);
}

__global__ __launch_bounds__(256) void k_prep_w(const float* __restrict__ W,
                                                short* __restrict__ Wbf) {
    int i = blockIdx.x * 256 + threadIdx.x;
    if (i < 128 * 128) Wbf[i] = f2bf(W[i]);
}

// MFMA GEMM: block = 256 thr = 4 waves, wave computes 16 nodes x 128 couts.
// A = x rows (cast to bf16 in-flight), B = Wbf rows (cout-major, contiguous k).
// Epilogue: xph fp16 store + fused l/r dot products via 16-lane shfl reduce.
__global__ __launch_bounds__(256) void k_gemm(const float* __restrict__ x,
                                              const short* __restrict__ Wbf,
                                              const float* __restrict__ attl,
                                              const float* __restrict__ attr,
                                              __half* __restrict__ xph,
                                              float* __restrict__ l,
                                              float* __restrict__ r, int N) {
    int t = threadIdx.x;
    int wave = t >> 6, lane = t & 63;
    int li = lane & 15, quad = lane >> 4;
    int base = blockIdx.x * 64 + wave * 16;

    f32x4 acc[8];
#pragma unroll
    for (int nt = 0; nt < 8; ++nt) acc[nt] = (f32x4){0.f, 0.f, 0.f, 0.f};

    int anode = base + li;
    bool avalid = anode < N;
    const float4* x4 = (const float4*)x;
    const short8* wb8 = (const short8*)Wbf;

#pragma unroll
    for (int kc = 0; kc < 4; ++kc) {
        float4 p0 = make_float4(0.f, 0.f, 0.f, 0.f), p1 = p0;
        if (avalid) {
            p0 = x4[(size_t)anode * 32 + kc * 8 + quad * 2];
            p1 = x4[(size_t)anode * 32 + kc * 8 + quad * 2 + 1];
        }
        short8 a;
        a[0] = f2bf(p0.x); a[1] = f2bf(p0.y); a[2] = f2bf(p0.z); a[3] = f2bf(p0.w);
        a[4] = f2bf(p1.x); a[5] = f2bf(p1.y); a[6] = f2bf(p1.z); a[7] = f2bf(p1.w);
#pragma unroll
        for (int nt = 0; nt < 8; ++nt) {
            short8 b = wb8[(nt * 16 + li) * 16 + kc * 4 + quad];
            acc[nt] = __builtin_amdgcn_mfma_f32_16x16x32_bf16(a, b, acc[nt], 0, 0, 0);
        }
    }

    // att factors for this lane's cout slice (couts 16*nt + li)
    float al0[4], al1[4], ar0[4], ar1[4];
#pragma unroll
    for (int h = 0; h < 4; ++h) {
        al0[h] = attl[h * 32 + li];
        al1[h] = attl[h * 32 + 16 + li];
        ar0[h] = attr[h * 32 + li];
        ar1[h] = attr[h * 32 + 16 + li];
    }

#pragma unroll
    for (int j = 0; j < 4; ++j) {
        int node = base + quad * 4 + j;
        bool valid = node < N;
        if (valid) {
#pragma unroll
            for (int nt = 0; nt < 8; ++nt)
                xph[(size_t)node * 128 + nt * 16 + li] = __float2half(acc[nt][j]);
        }
        float pl[4], pr[4];
#pragma unroll
        for (int h = 0; h < 4; ++h) {
            pl[h] = acc[2 * h][j] * al0[h] + acc[2 * h + 1][j] * al1[h];
            pr[h] = acc[2 * h][j] * ar0[h] + acc[2 * h + 1][j] * ar1[h];
        }
#pragma unroll
        for (int m = 1; m < 16; m <<= 1) {
#pragma unroll
            for (int h = 0; h < 4; ++h) {
                pl[h] += __shfl_xor(pl[h], m);
                pr[h] += __shfl_xor(pr[h], m);
            }
        }
        if (li == 0 && valid) {
            ((float4*)l)[node] = make_float4(pl[0], pl[1], pl[2], pl[3]);
            ((float4*)r)[node] = make_float4(pr[0], pr[1], pr[2], pr[3]);
        }
    }
}

// Bucket edges into group-partitioned 64-row slabs.
// group = (blockIdx&7)*4 | (waveid&3): XCD-affine lines, 32-way cursors.
__global__ __launch_bounds__(256) void k_fill(const int* __restrict__ ei,
                                              int* __restrict__ cur,
                                              unsigned int* __restrict__ slab, int E) {
    int tid = blockIdx.x * 256 + threadIdx.x;
    int g = ((blockIdx.x & 7) << 2) | ((threadIdx.x >> 6) & 3);
    int e0 = tid * 4;
    if (e0 >= E) return;
    if (e0 + 3 >= E) {
        for (int e = e0; e < E; ++e) {
            int row = ei[e], col = ei[E + e];
            int b = row >> 6;
            int pos = atomicAdd(&cur[b * NGROUP + g], 1);
            if (pos < CAP)
                slab[(size_t)(b * NGROUP + g) * CAP + pos] =
                    ((unsigned int)col << 6) | (unsigned int)(row & 63);
        }
        return;
    }
    int4 rows = ((const int4*)ei)[tid];
    int4 cols = ((const int4*)(ei + E))[tid];
    int rr[4] = {rows.x, rows.y, rows.z, rows.w};
    int cc[4] = {cols.x, cols.y, cols.z, cols.w};
#pragma unroll
    for (int j = 0; j < 4; ++j) {
        int b = rr[j] >> 6;
        int pos = atomicAdd(&cur[b * NGROUP + g], 1);
        if (pos < CAP)   // mean 32, CAP 96 = 11 sigma: never in practice
            slab[(size_t)(b * NGROUP + g) * CAP + pos] =
                ((unsigned int)cc[j] << 6) | (unsigned int)(rr[j] & 63);
    }
}

// One block per bucket, 512 threads = 8 waves.
// Phase A: concat 32 slab segments into LDS, counting-sort by local row.
// Phase B: one wave per row, 4 edges in flight (quarter-waves), register
// accumulation, shfl_xor(16,32) combine, fused normalize + bias.
__global__ __launch_bounds__(512) void k_tile(const int* __restrict__ cur,
                                              const unsigned int* __restrict__ slab,
                                              const float* __restrict__ l,
                                              const float* __restrict__ r,
                                              const __half* __restrict__ xph,
                                              const float* __restrict__ bias,
                                              float* __restrict__ out, int N) {
    __shared__ unsigned int s_packed[SLAB];   // 8 KB
    __shared__ int s_col[SLAB];               // 8 KB
    __shared__ int s_start[TILE_ROWS + 1];
    __shared__ int s_cursor[TILE_ROWS];
    __shared__ int s_cnt[TILE_ROWS];
    __shared__ int s_gcnt[NGROUP];
    __shared__ int s_goff[NGROUP + 1];

    int b = blockIdx.x;
    int base = b * TILE_ROWS;
    int t = threadIdx.x;

    if (t < TILE_ROWS) s_cnt[t] = 0;
    if (t < NGROUP) {
        int c = cur[b * NGROUP + t];
        if (c > CAP) c = CAP;
        s_gcnt[t] = c;
    }
    __syncthreads();
    if (t < NGROUP) {
        int v = s_gcnt[t];
#pragma unroll
        for (int off = 1; off < 32; off <<= 1) {
            int u = __shfl_up(v, off);
            if (t >= off) v += u;
        }
        s_goff[t + 1] = v;
        if (t == 0) s_goff[0] = 0;
    }
    __syncthreads();
    int tot = s_goff[NGROUP];
    if (tot > SLAB) tot = SLAB;

    for (int idx = t; idx < NGROUP * CAP; idx += 512) {
        int g = idx / CAP, i = idx - g * CAP;
        if (i < s_gcnt[g]) {
            int pos = s_goff[g] + i;
            if (pos < SLAB) {
                unsigned int p = slab[(size_t)(b * NGROUP + g) * CAP + i];
                s_packed[pos] = p;
                atomicAdd(&s_cnt[p & 63], 1);
            }
        }
    }
    __syncthreads();
    if (t < 64) {
        int c = s_cnt[t];
        int v = c;
#pragma unroll
        for (int off = 1; off < 64; off <<= 1) {
            int u = __shfl_up(v, off);
            if (t >= off) v += u;
        }
        s_start[t + 1] = v;
        if (t == 0) s_start[0] = 0;
        s_cursor[t] = v - c;   // exclusive
    }
    __syncthreads();
    for (int i = t; i < tot; i += 512) {
        unsigned int p = s_packed[i];
        int pos = atomicAdd(&s_cursor[p & 63], 1);
        s_col[pos] = (int)(p >> 6);
    }
    __syncthreads();

    int wave = t >> 6;
    int lane = t & 63;
    int quarter = lane >> 4;   // edge slot within wave (4 in flight)
    int li = lane & 15;        // channel block: fp16 chans 8li..8li+7
    int h = li >> 2;           // head of this channel block
    int rows = min(TILE_ROWS, N - base);
    const float4* xp4g = (const float4*)xph;  // 16B = 8 halves

    // bias slice for this lane (row-invariant)
    float4 b0 = ((const float4*)bias)[2 * li];
    float4 b1 = ((const float4*)bias)[2 * li + 1];

    for (int rl = wave; rl < rows; rl += 8) {
        int s0 = s_start[rl], s1 = s_start[rl + 1];
        float lh = l[(base + rl) * 4 + h];
        float a0 = 0.f, a1 = 0.f, a2 = 0.f, a3 = 0.f;
        float a4 = 0.f, a5 = 0.f, a6 = 0.f, a7 = 0.f;
        float dsum = 0.f;
#pragma unroll 2
        for (int i = s0 + quarter; i < s1; i += 4) {
            int col = s_col[i];
            float rh = r[col * 4 + h];
            float a = lh + rh;
            a = a >= 0.f ? a : NEG_SLOPE * a;
            float w = __expf(a);
            float4 raw = xp4g[(size_t)col * 16 + li];
            __half2* hp = (__half2*)&raw;
            float2 f0 = __half22float2(hp[0]);
            float2 f1 = __half22float2(hp[1]);
            float2 f2 = __half22float2(hp[2]);
            float2 f3 = __half22float2(hp[3]);
            a0 += w * f0.x; a1 += w * f0.y;
            a2 += w * f1.x; a3 += w * f1.y;
            a4 += w * f2.x; a5 += w * f2.y;
            a6 += w * f3.x; a7 += w * f3.y;
            dsum += w;
        }
        a0 += __shfl_xor(a0, 16); a0 += __shfl_xor(a0, 32);
        a1 += __shfl_xor(a1, 16); a1 += __shfl_xor(a1, 32);
        a2 += __shfl_xor(a2, 16); a2 += __shfl_xor(a2, 32);
        a3 += __shfl_xor(a3, 16); a3 += __shfl_xor(a3, 32);
        a4 += __shfl_xor(a4, 16); a4 += __shfl_xor(a4, 32);
        a5 += __shfl_xor(a5, 16); a5 += __shfl_xor(a5, 32);
        a6 += __shfl_xor(a6, 16); a6 += __shfl_xor(a6, 32);
        a7 += __shfl_xor(a7, 16); a7 += __shfl_xor(a7, 32);
        dsum += __shfl_xor(dsum, 16); dsum += __shfl_xor(dsum, 32);
        if (quarter == 0) {
            float inv = 1.f / (dsum + 1e-16f);
            float4 o0, o1;
            o0.x = a0 * inv + b0.x; o0.y = a1 * inv + b0.y;
            o0.z = a2 * inv + b0.z; o0.w = a3 * inv + b0.w;
            o1.x = a4 * inv + b1.x; o1.y = a5 * inv + b1.y;
            o1.z = a6 * inv + b1.z; o1.w = a7 * inv + b1.w;
            ((float4*)out)[(size_t)(base + rl) * 32 + 2 * li] = o0;
            ((float4*)out)[(size_t)(base + rl) * 32 + 2 * li + 1] = o1;
        }
    }
}

extern "C" void kernel_launch(void* const* d_in, const int* in_sizes, int n_in,
                              void* d_out, int out_size, void* d_ws, size_t ws_size,
                              hipStream_t stream) {
    const float* x    = (const float*)d_in[0];
    const int*   ei   = (const int*)d_in[1];
    const float* W    = (const float*)d_in[2];
    const float* attl = (const float*)d_in[3];
    const float* attr = (const float*)d_in[4];
    const float* bias = (const float*)d_in[5];
    int N = in_sizes[0] / 128;
    int E = in_sizes[1] / 2;
    int nbuckets = (N + TILE_ROWS - 1) / TILE_ROWS;

    char* ws = (char*)d_ws;
    __half* xph = (__half*)ws;              ws += (size_t)N * 128 * 2;         // 25.6 MB
    float* l    = (float*)ws;               ws += (size_t)N * 4 * 4;
    float* r    = (float*)ws;               ws += (size_t)N * 4 * 4;
    short* Wbf  = (short*)ws;               ws += 128 * 128 * 2;
    int* cur    = (int*)ws;                 ws += (size_t)nbuckets * NGROUP * 4;
    unsigned int* slab = (unsigned int*)ws; ws += (size_t)nbuckets * NGROUP * CAP * 4; // 19.2 MB

    float* out = (float*)d_out;

    hipMemsetAsync(cur, 0, (size_t)nbuckets * NGROUP * sizeof(int), stream);
    k_prep_w<<<64, 256, 0, stream>>>(W, Wbf);
    k_fill<<<((E / 4) + 255) / 256, 256, 0, stream>>>(ei, cur, slab, E);
    k_gemm<<<(N + 63) / 64, 256, 0, stream>>>(x, Wbf, attl, attr, xph, l, r, N);
    k_tile<<<nbuckets, 512, 0, stream>>>(cur, slab, l, r, xph, bias, out, N);
}

// Round 7
// 265.790 us; speedup vs baseline: 6.1257x; 1.0986x over previous
//
#include <hip/hip_runtime.h>
#include <hip/hip_fp16.h>

// GAT conv: N=100000, E=1.6M, IN_C=128, OUT_C=32, HEADS=4 (OC=128)
// Round 7:
//  - l/r folded into the GEMM as 8 augmented output columns (wl[h,:] =
//    sum_c attl[h,c] W[h*32+c,:]); kills the 128-shfl/thread epilogue.
//  - cur[] transposed to cur[g*nbuckets+b]: cursor lines become XCD-private
//    (was 16 g-classes per line -> cross-XCD ping-pong on every atomic).
//  - fill+gemm fused into one kernel (role split on blockIdx): atomic-latency
//    and HBM/MFMA pipes overlap instead of serializing.
//  - k_tile unchanged from Round 6 (79us) except cur layout.

constexpr float NEG_SLOPE = 0.2f;
constexpr int TILE_ROWS = 64;       // rows per bucket (row>>6)
constexpr int NGROUP = 32;          // slab partitions: 8 XCD classes x 4 waves
constexpr int CAP = 96;             // per-(bucket,group) capacity; mean 32
constexpr int SLAB = 2048;          // max edges per bucket staged in LDS

typedef __attribute__((ext_vector_type(8))) short short8;
typedef __attribute__((ext_vector_type(4))) float f32x4;

__device__ inline short f2bf(float f) {
    unsigned u = __float_as_uint(f);
    return (short)((u + 0x7fffu + ((u >> 16) & 1u)) >> 16);
}

// Build augmented bf16 weight Wa[144][128]:
//   rows 0..127  = W (cast)
//   rows 128+h   = wl[h,:] = sum_c attl[h,c] * W[h*32+c,:]
//   rows 132+h   = wr[h,:]
//   rows 136..143 = 0
__global__ __launch_bounds__(256) void k_prep(const float* __restrict__ W,
                                              const float* __restrict__ attl,
                                              const float* __restrict__ attr,
                                              short* __restrict__ Wa) {
    int blk = blockIdx.x;
    int t = threadIdx.x;
    if (blk < 64) {
        int i = blk * 256 + t;
        Wa[i] = f2bf(W[i]);
    } else if (blk == 64) {
        for (int s = t; s < 1024; s += 256) {
            int which = s >> 9;          // 0 = l, 1 = r
            int h = (s >> 7) & 3;
            int k = s & 127;
            const float* att = which ? attr : attl;
            float acc = 0.f;
#pragma unroll 8
            for (int c = 0; c < 32; ++c)
                acc += att[h * 32 + c] * W[(h * 32 + c) * 128 + k];
            Wa[(128 + which * 4 + h) * 128 + k] = f2bf(acc);
        }
    } else {
        int i = (blk - 65) * 256 + t;    // 1024 zero shorts (rows 136..143)
        if (i < 1024) Wa[136 * 128 + i] = 0;
    }
}

// Fused kernel: blocks [0, GB) do the MFMA GEMM (+ l/r columns),
// blocks [GB, GB+FB) do the edge bucketing fill. Independent work,
// complementary pipes (MFMA/HBM vs atomic latency).
__global__ __launch_bounds__(256) void k_main(const float* __restrict__ x,
                                              const short* __restrict__ Wa,
                                              const int* __restrict__ ei,
                                              __half* __restrict__ xph,
                                              float* __restrict__ l,
                                              float* __restrict__ r,
                                              int* __restrict__ cur,
                                              unsigned int* __restrict__ slab,
                                              int N, int E, int GB, int NB) {
    int t = threadIdx.x;
    if ((int)blockIdx.x >= GB) {
        // ---------------- fill role: 8 edges per thread ----------------
        int fb = blockIdx.x - GB;
        int tid = fb * 256 + t;
        int g = ((blockIdx.x & 7) << 2) | ((t >> 6) & 3);
        int e0 = tid * 8;
        if (e0 >= E) return;
        if (e0 + 7 < E) {
            int4 ra = ((const int4*)ei)[tid * 2];
            int4 rb = ((const int4*)ei)[tid * 2 + 1];
            int4 ca = ((const int4*)(ei + E))[tid * 2];
            int4 cb = ((const int4*)(ei + E))[tid * 2 + 1];
            int rr[8] = {ra.x, ra.y, ra.z, ra.w, rb.x, rb.y, rb.z, rb.w};
            int cc[8] = {ca.x, ca.y, ca.z, ca.w, cb.x, cb.y, cb.z, cb.w};
#pragma unroll
            for (int j = 0; j < 8; ++j) {
                int b = rr[j] >> 6;
                int pos = atomicAdd(&cur[g * NB + b], 1);
                if (pos < CAP)
                    slab[(size_t)(b * NGROUP + g) * CAP + pos] =
                        ((unsigned int)cc[j] << 6) | (unsigned int)(rr[j] & 63);
            }
        } else {
            for (int e = e0; e < E; ++e) {
                int row = ei[e], col = ei[E + e];
                int b = row >> 6;
                int pos = atomicAdd(&cur[g * NB + b], 1);
                if (pos < CAP)
                    slab[(size_t)(b * NGROUP + g) * CAP + pos] =
                        ((unsigned int)col << 6) | (unsigned int)(row & 63);
            }
        }
        return;
    }
    // ---------------- gemm role: wave computes 16 nodes x 144 couts --------
    int wave = t >> 6, lane = t & 63;
    int li = lane & 15, quad = lane >> 4;
    int base = blockIdx.x * 64 + wave * 16;

    f32x4 acc[9];
#pragma unroll
    for (int nt = 0; nt < 9; ++nt) acc[nt] = (f32x4){0.f, 0.f, 0.f, 0.f};

    int anode = base + li;
    bool avalid = anode < N;
    const float4* x4 = (const float4*)x;
    const short8* wb8 = (const short8*)Wa;

#pragma unroll
    for (int kc = 0; kc < 4; ++kc) {
        float4 p0 = make_float4(0.f, 0.f, 0.f, 0.f), p1 = p0;
        if (avalid) {
            p0 = x4[(size_t)anode * 32 + kc * 8 + quad * 2];
            p1 = x4[(size_t)anode * 32 + kc * 8 + quad * 2 + 1];
        }
        short8 a;
        a[0] = f2bf(p0.x); a[1] = f2bf(p0.y); a[2] = f2bf(p0.z); a[3] = f2bf(p0.w);
        a[4] = f2bf(p1.x); a[5] = f2bf(p1.y); a[6] = f2bf(p1.z); a[7] = f2bf(p1.w);
#pragma unroll
        for (int nt = 0; nt < 9; ++nt) {
            short8 b = wb8[(nt * 16 + li) * 16 + kc * 4 + quad];
            acc[nt] = __builtin_amdgcn_mfma_f32_16x16x32_bf16(a, b, acc[nt], 0, 0, 0);
        }
    }

#pragma unroll
    for (int j = 0; j < 4; ++j) {
        int node = base + quad * 4 + j;
        if (node >= N) continue;
#pragma unroll
        for (int nt = 0; nt < 8; ++nt)
            xph[(size_t)node * 128 + nt * 16 + li] = __float2half(acc[nt][j]);
        // augmented columns: li<4 -> l head li; li in [4,8) -> r head li-4
        if (li < 4)      l[node * 4 + li] = acc[8][j];
        else if (li < 8) r[node * 4 + li - 4] = acc[8][j];
    }
}

// One block per bucket, 512 threads = 8 waves. Unchanged from Round 6
// except cur[] layout (g*NB + b).
__global__ __launch_bounds__(512) void k_tile(const int* __restrict__ cur,
                                              const unsigned int* __restrict__ slab,
                                              const float* __restrict__ l,
                                              const float* __restrict__ r,
                                              const __half* __restrict__ xph,
                                              const float* __restrict__ bias,
                                              float* __restrict__ out, int N, int NB) {
    __shared__ unsigned int s_packed[SLAB];   // 8 KB
    __shared__ int s_col[SLAB];               // 8 KB
    __shared__ int s_start[TILE_ROWS + 1];
    __shared__ int s_cursor[TILE_ROWS];
    __shared__ int s_cnt[TILE_ROWS];
    __shared__ int s_gcnt[NGROUP];
    __shared__ int s_goff[NGROUP + 1];

    int b = blockIdx.x;
    int base = b * TILE_ROWS;
    int t = threadIdx.x;

    if (t < TILE_ROWS) s_cnt[t] = 0;
    if (t < NGROUP) {
        int c = cur[t * NB + b];
        if (c > CAP) c = CAP;
        s_gcnt[t] = c;
    }
    __syncthreads();
    if (t < NGROUP) {
        int v = s_gcnt[t];
#pragma unroll
        for (int off = 1; off < 32; off <<= 1) {
            int u = __shfl_up(v, off);
            if (t >= off) v += u;
        }
        s_goff[t + 1] = v;
        if (t == 0) s_goff[0] = 0;
    }
    __syncthreads();
    int tot = s_goff[NGROUP];
    if (tot > SLAB) tot = SLAB;

    for (int idx = t; idx < NGROUP * CAP; idx += 512) {
        int g = idx / CAP, i = idx - g * CAP;
        if (i < s_gcnt[g]) {
            int pos = s_goff[g] + i;
            if (pos < SLAB) {
                unsigned int p = slab[(size_t)(b * NGROUP + g) * CAP + i];
                s_packed[pos] = p;
                atomicAdd(&s_cnt[p & 63], 1);
            }
        }
    }
    __syncthreads();
    if (t < 64) {
        int c = s_cnt[t];
        int v = c;
#pragma unroll
        for (int off = 1; off < 64; off <<= 1) {
            int u = __shfl_up(v, off);
            if (t >= off) v += u;
        }
        s_start[t + 1] = v;
        if (t == 0) s_start[0] = 0;
        s_cursor[t] = v - c;   // exclusive
    }
    __syncthreads();
    for (int i = t; i < tot; i += 512) {
        unsigned int p = s_packed[i];
        int pos = atomicAdd(&s_cursor[p & 63], 1);
        s_col[pos] = (int)(p >> 6);
    }
    __syncthreads();

    int wave = t >> 6;
    int lane = t & 63;
    int quarter = lane >> 4;   // edge slot within wave (4 in flight)
    int li = lane & 15;        // channel block: fp16 chans 8li..8li+7
    int h = li >> 2;           // head of this channel block
    int rows = min(TILE_ROWS, N - base);
    const float4* xp4g = (const float4*)xph;  // 16B = 8 halves

    float4 b0 = ((const float4*)bias)[2 * li];
    float4 b1 = ((const float4*)bias)[2 * li + 1];

    for (int rl = wave; rl < rows; rl += 8) {
        int s0 = s_start[rl], s1 = s_start[rl + 1];
        float lh = l[(base + rl) * 4 + h];
        float a0 = 0.f, a1 = 0.f, a2 = 0.f, a3 = 0.f;
        float a4 = 0.f, a5 = 0.f, a6 = 0.f, a7 = 0.f;
        float dsum = 0.f;
#pragma unroll 2
        for (int i = s0 + quarter; i < s1; i += 4) {
            int col = s_col[i];
            float rh = r[col * 4 + h];
            float a = lh + rh;
            a = a >= 0.f ? a : NEG_SLOPE * a;
            float w = __expf(a);
            float4 raw = xp4g[(size_t)col * 16 + li];
            __half2* hp = (__half2*)&raw;
            float2 f0 = __half22float2(hp[0]);
            float2 f1 = __half22float2(hp[1]);
            float2 f2 = __half22float2(hp[2]);
            float2 f3 = __half22float2(hp[3]);
            a0 += w * f0.x; a1 += w * f0.y;
            a2 += w * f1.x; a3 += w * f1.y;
            a4 += w * f2.x; a5 += w * f2.y;
            a6 += w * f3.x; a7 += w * f3.y;
            dsum += w;
        }
        a0 += __shfl_xor(a0, 16); a0 += __shfl_xor(a0, 32);
        a1 += __shfl_xor(a1, 16); a1 += __shfl_xor(a1, 32);
        a2 += __shfl_xor(a2, 16); a2 += __shfl_xor(a2, 32);
        a3 += __shfl_xor(a3, 16); a3 += __shfl_xor(a3, 32);
        a4 += __shfl_xor(a4, 16); a4 += __shfl_xor(a4, 32);
        a5 += __shfl_xor(a5, 16); a5 += __shfl_xor(a5, 32);
        a6 += __shfl_xor(a6, 16); a6 += __shfl_xor(a6, 32);
        a7 += __shfl_xor(a7, 16); a7 += __shfl_xor(a7, 32);
        dsum += __shfl_xor(dsum, 16); dsum += __shfl_xor(dsum, 32);
        if (quarter == 0) {
            float inv = 1.f / (dsum + 1e-16f);
            float4 o0, o1;
            o0.x = a0 * inv + b0.x; o0.y = a1 * inv + b0.y;
            o0.z = a2 * inv + b0.z; o0.w = a3 * inv + b0.w;
            o1.x = a4 * inv + b1.x; o1.y = a5 * inv + b1.y;
            o1.z = a6 * inv + b1.z; o1.w = a7 * inv + b1.w;
            ((float4*)out)[(size_t)(base + rl) * 32 + 2 * li] = o0;
            ((float4*)out)[(size_t)(base + rl) * 32 + 2 * li + 1] = o1;
        }
    }
}

extern "C" void kernel_launch(void* const* d_in, const int* in_sizes, int n_in,
                              void* d_out, int out_size, void* d_ws, size_t ws_size,
                              hipStream_t stream) {
    const float* x    = (const float*)d_in[0];
    const int*   ei   = (const int*)d_in[1];
    const float* W    = (const float*)d_in[2];
    const float* attl = (const float*)d_in[3];
    const float* attr = (const float*)d_in[4];
    const float* bias = (const float*)d_in[5];
    int N = in_sizes[0] / 128;
    int E = in_sizes[1] / 2;
    int nbuckets = (N + TILE_ROWS - 1) / TILE_ROWS;

    char* ws = (char*)d_ws;
    __half* xph = (__half*)ws;              ws += (size_t)N * 128 * 2;         // 25.6 MB
    float* l    = (float*)ws;               ws += (size_t)N * 4 * 4;
    float* r    = (float*)ws;               ws += (size_t)N * 4 * 4;
    short* Wa   = (short*)ws;               ws += 144 * 128 * 2;
    int* cur    = (int*)ws;                 ws += (size_t)nbuckets * NGROUP * 4;
    unsigned int* slab = (unsigned int*)ws; ws += (size_t)nbuckets * NGROUP * CAP * 4;

    float* out = (float*)d_out;

    int GB = (N + 63) / 64;                       // gemm blocks
    int FB = ((E + 7) / 8 + 255) / 256;           // fill blocks (8 edges/thread)

    hipMemsetAsync(cur, 0, (size_t)nbuckets * NGROUP * sizeof(int), stream);
    k_prep<<<69, 256, 0, stream>>>(W, attl, attr, Wa);
    k_main<<<GB + FB, 256, 0, stream>>>(x, Wa, ei, xph, l, r, cur, slab, N, E, GB, nbuckets);
    k_tile<<<nbuckets, 512, 0, stream>>>(cur, slab, l, r, xph, bias, out, N, nbuckets);
}